// Round 17
// baseline (239.284 us; speedup 1.0000x reference)
//
#include <hip/hip_runtime.h>
#include <hip/hip_bf16.h>
#include <cstdint>
#include <cstddef>

typedef float f32x4 __attribute__((ext_vector_type(4)));
typedef float f32x16 __attribute__((ext_vector_type(16)));
typedef __bf16 bf16x8 __attribute__((ext_vector_type(8)));
typedef unsigned short us8v __attribute__((ext_vector_type(8)));
typedef unsigned short us4v __attribute__((ext_vector_type(4)));

constexpr int B_ = 2, S_ = 2048, D_ = 2048, NH = 16, NKV = 4, HD = 128;
constexpr int QKV_O = (NH + 2 * NKV) * HD;  // 3072

__device__ __forceinline__ unsigned short f2b(float f) {
  union { float f; uint32_t u; } v{f};
  uint32_t r = v.u + 0x7fffu + ((v.u >> 16) & 1u);  // RNE
  return (unsigned short)(r >> 16);
}

__device__ __forceinline__ float b2f(unsigned short u) {
  union { uint32_t u; float f; } v;
  v.u = ((uint32_t)u) << 16;
  return v.f;
}

__device__ __forceinline__ uint32_t pk2(float a, float b) {
  union { __bf16 h[2]; uint32_t u; } v;
  v.h[0] = (__bf16)a; v.h[1] = (__bf16)b;
  return v.u;
}

__device__ __forceinline__ bf16x8 as_bf(us8v x) {
  union { us8v u; bf16x8 b; } v; v.u = x; return v.b;
}

__device__ __forceinline__ f32x4 mfma16(bf16x8 a, bf16x8 b, f32x4 c) {
  return __builtin_amdgcn_mfma_f32_16x16x32_bf16(a, b, c, 0, 0, 0);
}
__device__ __forceinline__ f32x16 mfma32(bf16x8 a, bf16x8 b, f32x16 c) {
  return __builtin_amdgcn_mfma_f32_32x32x16_bf16(a, b, c, 0, 0, 0);
}

// async global->LDS, 16B per lane; LDS dest = wave-uniform base + lane*16
__device__ __forceinline__ void gload_lds16(const unsigned short* g, unsigned short* l) {
  __builtin_amdgcn_global_load_lds(
      (const __attribute__((address_space(1))) unsigned int*)(uintptr_t)g,
      (__attribute__((address_space(3))) unsigned int*)(uintptr_t)l, 16, 0, 0);
}

// ---------------- f32 -> bf16 conversion (vectorized) ----------------
__global__ void f2b_kernel(const float* __restrict__ in, unsigned short* __restrict__ out, int n4) {
  int i = blockIdx.x * blockDim.x + threadIdx.x;
  if (i >= n4) return;
  float4 v = reinterpret_cast<const float4*>(in)[i];
  us4v o;
  o[0] = f2b(v.x); o[1] = f2b(v.y); o[2] = f2b(v.z); o[3] = f2b(v.w);
  reinterpret_cast<us4v*>(out)[i] = o;
}

// ---------------- RoPE cos/sin table: [S][64] ----------------
__global__ void rope_table_kernel(float* __restrict__ cs, float* __restrict__ sn) {
  int idx = blockIdx.x * blockDim.x + threadIdx.x;
  if (idx >= S_ * 64) return;
  int t = idx >> 6, i = idx & 63;
  float inv = __expf(-((float)(2 * i) / 128.0f) * 9.210340371976184f);
  float fr = (float)t * inv;
  cs[idx] = cosf(fr);
  sn[idx] = sinf(fr);
}

// ---------------- RoPE apply (bf16 qkv in); Q pre-scaled by scale*log2e; K -> K2 ----------------
__global__ void rope_qk_kernel(const unsigned short* __restrict__ qkv, const float* __restrict__ cs,
                               const float* __restrict__ sn, unsigned short* __restrict__ Q,
                               unsigned short* __restrict__ K2) {
  int idx = blockIdx.x * blockDim.x + threadIdx.x;
  if (idx >= B_ * S_ * 20 * 64) return;
  int pr = idx & 63;
  int tmp = idx >> 6;
  int hh = tmp % 20; tmp /= 20;
  int s = tmp % S_;
  int b = tmp / S_;
  int off = (hh < 16) ? hh * HD : NH * HD + (hh - 16) * HD;
  unsigned pv = *reinterpret_cast<const unsigned*>(qkv + (size_t)(b * S_ + s) * QKV_O + off + 2 * pr);
  float vx = b2f((unsigned short)(pv & 0xffff));
  float vy = b2f((unsigned short)(pv >> 16));
  float c0 = cs[s * 64 + pr], s0 = sn[s * 64 + pr];
  // fold attn scale AND log2(e) into Q: softmax runs in exp2 domain
  float mult = (hh < 16) ? 0.12751744f : 1.0f;
  float o0 = (vx * c0 - vy * s0) * mult;
  float o1 = (vx * s0 + vy * c0) * mult;
  unsigned int packed = (unsigned)f2b(o0) | ((unsigned)f2b(o1) << 16);
  if (hh < 16) {
    *reinterpret_cast<unsigned*>(Q + (((size_t)(b * NH + hh) * S_ + s) * HD + 2 * pr)) = packed;
  } else {
    int bk = b * NKV + (hh - 16);
    size_t a = (((size_t)bk * 16 + (pr >> 2)) * S_ + s) * 8 + (pr & 3) * 2;
    *reinterpret_cast<unsigned*>(K2 + a) = packed;
  }
}

// ---------------- V pack: qkv bf16 -> V2 bf16 [bk][s/8][d=128][8] (pure relayout) ----------------
__global__ __launch_bounds__(128) void v8_kernel(const unsigned short* __restrict__ qkv,
                                                 unsigned short* __restrict__ V2) {
  int d = threadIdx.x;          // 0..127
  int g = blockIdx.x;           // s-group 0..255
  int bk = blockIdx.y;          // b*4+kvh
  const unsigned short* src = qkv + (size_t)((bk >> 2) * S_ + g * 8) * QKV_O + (NH + NKV) * HD +
                              (bk & 3) * HD + d;
  us8v o;
#pragma unroll
  for (int j = 0; j < 8; j++) o[j] = src[(size_t)j * QKV_O];
  *reinterpret_cast<us8v*>(V2 + (((size_t)bk * 256 + g) * 128 + d) * 8) = o;
}

// ---------------- bf16 GEMM (256x192 8-phase): C(bf16) = A * B^T, 256 blocks = 1/CU ----------------
__global__ __launch_bounds__(512, 2) void gemm8p192_kernel(const unsigned short* __restrict__ A,
                                                           const unsigned short* __restrict__ Bm,
                                                           unsigned short* __restrict__ C, int M,
                                                           int N, int K, int nbx) {
  __shared__ unsigned short LDS[57344];  // A: 2x16384 elems; B at 32768 + 2x12288 elems
  const int t = threadIdx.x;
  const int lane = t & 63, wid = t >> 6;
  const int wm = wid >> 2, wn = wid & 3;
  const int c = lane & 15, g4 = lane >> 4;
  const int cpx = gridDim.x >> 3;
  const int nid = (blockIdx.x & 7) * cpx + (blockIdx.x >> 3);
  const int m0 = (nid / nbx) * 256, n0 = (nid % nbx) * 192;

  const int sr = t >> 3, ss = t & 7;
  const int sg = ss ^ (sr & 7);
  const unsigned short* pa = A + (size_t)(m0 + sr) * K + sg * 8;
  const unsigned short* pb = Bm + (size_t)(n0 + sr) * K + sg * 8;
  unsigned short* ldw = (unsigned short*)&LDS[wid << 9];

  f32x4 acc[8][3] = {};
  bf16x8 bf[3][2];

#define STAGE_A(buf, j, kk0) \
  gload_lds16(pa + (size_t)(64 * (j)) * K + (kk0), ldw + (buf)*16384 + (j)*4096)
#define STAGE_B(buf, j, kk0) \
  gload_lds16(pb + (size_t)(64 * (j)) * K + (kk0), ldw + 32768 + (buf)*12288 + (j)*4096)

#define LDA(buf, m, kk) \
  as_bf(*reinterpret_cast<const us8v*>( \
      &LDS[(buf)*16384 + (wm * 128 + (m)*16 + c) * 64 + ((((kk) << 2) | g4) ^ (c & 7)) * 8]))
#define LDB(buf, n, kk) \
  as_bf(*reinterpret_cast<const us8v*>( \
      &LDS[32768 + (buf)*12288 + (wn * 48 + (n)*16 + c) * 64 + ((((kk) << 2) | g4) ^ (c & 7)) * 8]))

#pragma unroll
  for (int j = 0; j < 3; j++) STAGE_B(0, j, 0);
#pragma unroll
  for (int j = 0; j < 4; j++) STAGE_A(0, j, 0);
  asm volatile("s_waitcnt vmcnt(0)" ::: "memory");
  __builtin_amdgcn_s_barrier();

  const int NT = K >> 6;
  for (int tt = 0; tt < NT; ++tt) {
    const int cur = tt & 1, nxt = cur ^ 1;
    const int kn = (tt + 1) << 6;
    const bool st = (tt + 1) < NT;
    bf16x8 a00, a01, a10, a11;

#define MFMA_PAIR(mlo)                                    \
  __builtin_amdgcn_s_setprio(1);                          \
  _Pragma("unroll") for (int n = 0; n < 3; n++) {         \
    acc[(mlo)][n] = mfma16(a00, bf[n][0], acc[(mlo)][n]); \
    acc[(mlo) + 1][n] = mfma16(a10, bf[n][0], acc[(mlo) + 1][n]); \
    acc[(mlo)][n] = mfma16(a01, bf[n][1], acc[(mlo)][n]); \
    acc[(mlo) + 1][n] = mfma16(a11, bf[n][1], acc[(mlo) + 1][n]); \
  }                                                       \
  __builtin_amdgcn_s_setprio(0);

    // ---- P0 ----
#pragma unroll
    for (int n = 0; n < 3; n++) { bf[n][0] = LDB(cur, n, 0); bf[n][1] = LDB(cur, n, 1); }
    a00 = LDA(cur, 0, 0); a01 = LDA(cur, 0, 1); a10 = LDA(cur, 1, 0); a11 = LDA(cur, 1, 1);
    if (st) { STAGE_B(nxt, 0, kn); STAGE_B(nxt, 1, kn); }
    __builtin_amdgcn_s_barrier();
    MFMA_PAIR(0)
    __builtin_amdgcn_s_barrier();
    // ---- P1 ----
    a00 = LDA(cur, 2, 0); a01 = LDA(cur, 2, 1); a10 = LDA(cur, 3, 0); a11 = LDA(cur, 3, 1);
    if (st) STAGE_B(nxt, 2, kn);
    asm volatile("s_waitcnt vmcnt(3)" ::: "memory");
    __builtin_amdgcn_s_barrier();
    MFMA_PAIR(2)
    __builtin_amdgcn_s_barrier();
    // ---- P2 ----
    a00 = LDA(cur, 4, 0); a01 = LDA(cur, 4, 1); a10 = LDA(cur, 5, 0); a11 = LDA(cur, 5, 1);
    if (st) { STAGE_A(nxt, 0, kn); STAGE_A(nxt, 2, kn); }
    __builtin_amdgcn_s_barrier();
    MFMA_PAIR(4)
    __builtin_amdgcn_s_barrier();
    // ---- P3 ----
    a00 = LDA(cur, 6, 0); a01 = LDA(cur, 6, 1); a10 = LDA(cur, 7, 0); a11 = LDA(cur, 7, 1);
    if (st) { STAGE_A(nxt, 1, kn); STAGE_A(nxt, 3, kn); }
    asm volatile("s_waitcnt vmcnt(2)" ::: "memory");
    __builtin_amdgcn_s_barrier();
    MFMA_PAIR(6)
    __builtin_amdgcn_s_barrier();
#undef MFMA_PAIR
  }

#pragma unroll
  for (int m = 0; m < 8; m++)
#pragma unroll
    for (int n = 0; n < 3; n++)
#pragma unroll
      for (int r = 0; r < 4; r++)
        C[(size_t)(m0 + wm * 128 + m * 16 + g4 * 4 + r) * N + n0 + wn * 48 + n * 16 + c] =
            f2b(acc[m][n][r]);
#undef STAGE_A
#undef STAGE_B
#undef LDA
#undef LDB
}

// ---------------- bf16 GEMM (256x128 8-phase, f32 C): out-proj, 100% CU fill ----------------
__global__ __launch_bounds__(512, 2) void gemm8pn_kernel(const unsigned short* __restrict__ A,
                                                         const unsigned short* __restrict__ Bm,
                                                         float* __restrict__ C, int M, int N,
                                                         int K, int nbx) {
  __shared__ unsigned short LDS[49152];  // A: [2][16384]; B at 32768 + [2][8192]
  const int t = threadIdx.x;
  const int lane = t & 63, wid = t >> 6;
  const int wm = wid >> 2, wn = wid & 3;
  const int c = lane & 15, g4 = lane >> 4;
  const int cpx = gridDim.x >> 3;
  const int nid = (blockIdx.x & 7) * cpx + (blockIdx.x >> 3);
  const int m0 = (nid / nbx) * 256, n0 = (nid % nbx) * 128;

  const int sr = t >> 3, ss = t & 7;
  const int sg = ss ^ (sr & 7);
  const unsigned short* pa = A + (size_t)(m0 + sr) * K + sg * 8;
  const unsigned short* pb = Bm + (size_t)(n0 + sr) * K + sg * 8;
  unsigned short* ldw = (unsigned short*)&LDS[wid << 9];

  f32x4 acc[8][2] = {};
  bf16x8 bf[2][2];

#define STAGE_A(buf, j, kk0) \
  gload_lds16(pa + (size_t)(64 * (j)) * K + (kk0), ldw + (buf)*16384 + (j)*4096)
#define STAGE_B(buf, j, kk0) \
  gload_lds16(pb + (size_t)(64 * (j)) * K + (kk0), ldw + 32768 + (buf)*8192 + (j)*4096)

#define LDA(buf, m, kk) \
  as_bf(*reinterpret_cast<const us8v*>( \
      &LDS[(buf)*16384 + (wm * 128 + (m)*16 + c) * 64 + ((((kk) << 2) | g4) ^ (c & 7)) * 8]))
#define LDB(buf, n, kk) \
  as_bf(*reinterpret_cast<const us8v*>( \
      &LDS[32768 + (buf)*8192 + (wn * 32 + (n)*16 + c) * 64 + ((((kk) << 2) | g4) ^ (c & 7)) * 8]))

  STAGE_B(0, 0, 0); STAGE_B(0, 1, 0);
#pragma unroll
  for (int j = 0; j < 4; j++) STAGE_A(0, j, 0);
  asm volatile("s_waitcnt vmcnt(0)" ::: "memory");
  __builtin_amdgcn_s_barrier();

  const int NT = K >> 6;
  for (int tt = 0; tt < NT; ++tt) {
    const int cur = tt & 1, nxt = cur ^ 1;
    const int kn = (tt + 1) << 6;
    const bool st = (tt + 1) < NT;
    bf16x8 a00, a01, a10, a11;

#define MFMA_PAIR(mlo)                                    \
  __builtin_amdgcn_s_setprio(1);                          \
  _Pragma("unroll") for (int n = 0; n < 2; n++) {         \
    acc[(mlo)][n] = mfma16(a00, bf[n][0], acc[(mlo)][n]); \
    acc[(mlo) + 1][n] = mfma16(a10, bf[n][0], acc[(mlo) + 1][n]); \
    acc[(mlo)][n] = mfma16(a01, bf[n][1], acc[(mlo)][n]); \
    acc[(mlo) + 1][n] = mfma16(a11, bf[n][1], acc[(mlo) + 1][n]); \
  }                                                       \
  __builtin_amdgcn_s_setprio(0);

    // ---- P0 ----
#pragma unroll
    for (int n = 0; n < 2; n++) { bf[n][0] = LDB(cur, n, 0); bf[n][1] = LDB(cur, n, 1); }
    a00 = LDA(cur, 0, 0); a01 = LDA(cur, 0, 1); a10 = LDA(cur, 1, 0); a11 = LDA(cur, 1, 1);
    if (st) STAGE_B(nxt, 0, kn);
    __builtin_amdgcn_s_barrier();
    MFMA_PAIR(0)
    __builtin_amdgcn_s_barrier();
    // ---- P1 ----
    a00 = LDA(cur, 2, 0); a01 = LDA(cur, 2, 1); a10 = LDA(cur, 3, 0); a11 = LDA(cur, 3, 1);
    if (st) STAGE_B(nxt, 1, kn);
    asm volatile("s_waitcnt vmcnt(2)" ::: "memory");
    __builtin_amdgcn_s_barrier();
    MFMA_PAIR(2)
    __builtin_amdgcn_s_barrier();
    // ---- P2 ----
    a00 = LDA(cur, 4, 0); a01 = LDA(cur, 4, 1); a10 = LDA(cur, 5, 0); a11 = LDA(cur, 5, 1);
    if (st) { STAGE_A(nxt, 0, kn); STAGE_A(nxt, 2, kn); }
    __builtin_amdgcn_s_barrier();
    MFMA_PAIR(4)
    __builtin_amdgcn_s_barrier();
    // ---- P3 ----
    a00 = LDA(cur, 6, 0); a01 = LDA(cur, 6, 1); a10 = LDA(cur, 7, 0); a11 = LDA(cur, 7, 1);
    if (st) { STAGE_A(nxt, 1, kn); STAGE_A(nxt, 3, kn); }
    asm volatile("s_waitcnt vmcnt(2)" ::: "memory");
    __builtin_amdgcn_s_barrier();
    MFMA_PAIR(6)
    __builtin_amdgcn_s_barrier();
#undef MFMA_PAIR
  }

#pragma unroll
  for (int m = 0; m < 8; m++)
#pragma unroll
    for (int n = 0; n < 2; n++)
#pragma unroll
      for (int r = 0; r < 4; r++)
        C[(size_t)(m0 + wm * 128 + m * 16 + g4 * 4 + r) * N + n0 + wn * 32 + n * 16 + c] =
            acc[m][n][r];
#undef STAGE_A
#undef STAGE_B
#undef LDA
#undef LDB
}

// ---------------- Flash attention: r12 schedule + K&V ping-pong, waves_per_eu(2,2) ----------------
// amdgpu_waves_per_eu(2,2) pins the allocator to the 2-wave/SIMD tier (256 VGPR budget)
// so the +32 VGPR V double-buffer allocates without spilling (r14's failure mode).
// Occupancy unchanged: 256 blocks = 1 block/CU = 8 waves/CU either way.
__global__ __launch_bounds__(512) __attribute__((amdgpu_waves_per_eu(2, 2))) void attn32_kernel(
    const unsigned short* __restrict__ Q, const unsigned short* __restrict__ K2,
    const unsigned short* __restrict__ V2, unsigned short* __restrict__ O) {
  int t = threadIdx.x;
  int lane = t & 63, wid = t >> 6;
  int l31 = lane & 31, hi = lane >> 5;

  int id = blockIdx.x;
  int g = id & 7, s5 = id >> 3;          // g = (b,kvh) group -> XCD g; s5 = 0..31
  int b = g >> 2, kvh = g & 3;
  int h = kvh * 4 + (s5 & 3);
  int bk = b * NKV + kvh;
  int a = (s5 >> 2) * 4 + (wid & 3);     // pair index 0..31
  int tw = (wid >> 2) ? (63 - a) : a;    // cheap on SIMD w, heavy on same SIMD (w+4)
  int qw = tw * 32;

  const unsigned short* Qp = Q + ((size_t)(b * NH + h) * S_ + qw) * HD + (size_t)l31 * HD + hi * 8;
  const unsigned short* Kp = K2 + (((size_t)bk * 16 + hi) * S_ + l31) * 8;
  const unsigned short* Vp = V2 + (((size_t)bk * 256 + hi) * 128 + l31) * 8;

  bf16x8 qf[8];
#pragma unroll
  for (int kk = 0; kk < 8; kk++)
    qf[kk] = as_bf(*reinterpret_cast<const us8v*>(Qp + kk * 16));

  f32x16 oacc[4] = {};
  float mrow = -1e30f, lsum = 0.0f;

  bf16x8 kA[8], kB[8], vA[8], vB[8];

  auto loadK = [&](bf16x8(&kf)[8], int kv) {
    const unsigned short* kp = Kp + (size_t)kv * 8;
#pragma unroll
    for (int kk = 0; kk < 8; kk++)
      kf[kk] = as_bf(*reinterpret_cast<const us8v*>(kp + (size_t)kk * 2 * S_ * 8));
  };
  auto loadV = [&](bf16x8(&vf)[8], int kv) {
    const unsigned short* vp = Vp + (size_t)kv * 128;
#pragma unroll
    for (int dt = 0; dt < 4; dt++) {
      vf[2 * dt] = as_bf(*reinterpret_cast<const us8v*>(vp + dt * 256));
      vf[2 * dt + 1] = as_bf(*reinterpret_cast<const us8v*>(vp + 2048 + dt * 256));
    }
  };

  auto step = [&](bf16x8(&kf)[8], bf16x8(&kn)[8], bf16x8(&vf)[8], bf16x8(&vn)[8], int kv0) {
    // prefetch next step's K AND V (consumed one full step later)
    if (kv0 + 32 <= qw) { loadK(kn, kv0 + 32); loadV(vn, kv0 + 32); }

    f32x16 sa = {}, sb = {};
    __builtin_amdgcn_s_setprio(1);
#pragma unroll
    for (int kk = 0; kk < 4; kk++) {
      sa = mfma32(kf[2 * kk], qf[2 * kk], sa);
      sb = mfma32(kf[2 * kk + 1], qf[2 * kk + 1], sb);
    }
    __builtin_amdgcn_s_setprio(0);
    f32x16 s = sa + sb;

    if (kv0 == qw) {  // diagonal tile: causal mask
      int qg = qw + l31;
#pragma unroll
      for (int r = 0; r < 16; r++) {
        int kvg = kv0 + (r & 3) + 8 * (r >> 2) + 4 * hi;
        if (kvg > qg) s[r] = -1e30f;
      }
    }

    float pm = fmaxf(s[0], s[1]);
#pragma unroll
    for (int r = 2; r < 16; r++) pm = fmaxf(pm, s[r]);
    pm = fmaxf(pm, __shfl_xor(pm, 32));

    bool nore = __all(pm <= mrow + 11.54f) != 0;  // defer-max, log2 units
    float mn = nore ? mrow : fmaxf(mrow, pm);
    float part = 0.0f;
    uint32_t w[8];
#pragma unroll
    for (int jj = 0; jj < 8; jj++) {
      float e0 = __builtin_amdgcn_exp2f(s[2 * jj] - mn);
      float e1 = __builtin_amdgcn_exp2f(s[2 * jj + 1] - mn);
      part += e0 + e1;
      w[jj] = pk2(e0, e1);
    }
    part += __shfl_xor(part, 32);
    if (nore) {
      lsum += part;
    } else {
      float alpha = __builtin_amdgcn_exp2f(mrow - mn);  // per q-row l31
      lsum = lsum * alpha + part;
      mrow = mn;
#pragma unroll
      for (int r = 0; r < 16; r++) {
        float af = __shfl(alpha, (r & 3) + 8 * (r >> 2) + 4 * hi);
#pragma unroll
        for (int dt = 0; dt < 4; dt++) oacc[dt][r] *= af;
      }
    }

    // ---- P -> A-fragments via lane^32 exchange ----
    uint32_t sw[8];
#pragma unroll
    for (int jj = 0; jj < 8; jj++) sw[jj] = __shfl_xor(w[jj], 32);
    union { uint32_t u[4]; bf16x8 v; } pa0, pa1;
    if (hi == 0) {
      pa0.u[0] = w[0]; pa0.u[1] = w[1]; pa0.u[2] = sw[0]; pa0.u[3] = sw[1];
      pa1.u[0] = w[4]; pa1.u[1] = w[5]; pa1.u[2] = sw[4]; pa1.u[3] = sw[5];
    } else {
      pa0.u[0] = sw[2]; pa0.u[1] = sw[3]; pa0.u[2] = w[2]; pa0.u[3] = w[3];
      pa1.u[0] = sw[6]; pa1.u[1] = sw[7]; pa1.u[2] = w[6]; pa1.u[3] = w[7];
    }

    __builtin_amdgcn_s_setprio(1);
#pragma unroll
    for (int dt = 0; dt < 4; dt++) {
      oacc[dt] = mfma32(pa0.v, vf[2 * dt], oacc[dt]);
      oacc[dt] = mfma32(pa1.v, vf[2 * dt + 1], oacc[dt]);
    }
    __builtin_amdgcn_s_setprio(0);
  };

  loadK(kA, 0);
  loadV(vA, 0);
  int kv0 = 0;
  while (true) {
    step(kA, kB, vA, vB, kv0);
    kv0 += 32;
    if (kv0 > qw) break;
    step(kB, kA, vB, vA, kv0);
    kv0 += 32;
    if (kv0 > qw) break;
  }

  // ---- epilogue: O[q=crow(r,hi)][d=dt*32+l31] ----
  float il = 1.0f / lsum;
  unsigned short* Op = O + ((size_t)b * S_ + qw) * D_ + h * HD;
#pragma unroll
  for (int r = 0; r < 16; r++) {
    int row = (r & 3) + 8 * (r >> 2) + 4 * hi;
    float sc = __shfl(il, row);
#pragma unroll
    for (int dt = 0; dt < 4; dt++)
      Op[(size_t)row * D_ + dt * 32 + l31] = f2b(oacc[dt][r] * sc);
  }
}

extern "C" void kernel_launch(void* const* d_in, const int* in_sizes, int n_in, void* d_out,
                              int out_size, void* d_ws, size_t ws_size, hipStream_t stream) {
  const float* x = (const float*)d_in[0];
  const float* w_qkv = (const float*)d_in[1];
  const float* w_o = (const float*)d_in[2];
  float* out = (float*)d_out;

  char* ws = (char*)d_ws;
  size_t off = 0;
  auto alloc = [&](size_t bytes) -> void* {
    void* p = ws + off;
    off += (bytes + 255) & ~(size_t)255;
    return p;
  };
  const size_t nx = (size_t)B_ * S_ * D_;
  const size_t nwqkv = (size_t)QKV_O * D_;
  const size_t nwo = (size_t)D_ * D_;
  unsigned short* xb = (unsigned short*)alloc(nx * 2);
  unsigned short* wqkvb = (unsigned short*)alloc(nwqkv * 2);
  unsigned short* wob = (unsigned short*)alloc(nwo * 2);
  unsigned short* qkvb = (unsigned short*)alloc((size_t)B_ * S_ * QKV_O * 2);  // bf16
  unsigned short* Qb = (unsigned short*)alloc((size_t)B_ * NH * S_ * HD * 2);
  unsigned short* K2b = (unsigned short*)alloc((size_t)B_ * NKV * S_ * HD * 2);
  unsigned short* V2b = (unsigned short*)alloc((size_t)B_ * NKV * HD * S_ * 2);
  unsigned short* attnb = (unsigned short*)alloc((size_t)B_ * S_ * D_ * 2);
  float* cs = (float*)alloc((size_t)S_ * 64 * 4);
  float* sn = (float*)alloc((size_t)S_ * 64 * 4);

  f2b_kernel<<<dim3((nx / 4 + 255) / 256), 256, 0, stream>>>(x, xb, nx / 4);
  f2b_kernel<<<dim3((nwqkv / 4 + 255) / 256), 256, 0, stream>>>(w_qkv, wqkvb, nwqkv / 4);
  f2b_kernel<<<dim3((nwo / 4 + 255) / 256), 256, 0, stream>>>(w_o, wob, nwo / 4);
  rope_table_kernel<<<dim3((S_ * 64 + 255) / 256), 256, 0, stream>>>(cs, sn);

  // qkv: 256x192 tiles, grid 16*16 = 256 = exactly 1 block/CU
  gemm8p192_kernel<<<dim3(256), 512, 0, stream>>>(xb, wqkvb, qkvb, B_ * S_, QKV_O, D_,
                                                  QKV_O / 192);

  rope_qk_kernel<<<dim3((B_ * S_ * 20 * 64 + 255) / 256), 256, 0, stream>>>(qkvb, cs, sn, Qb, K2b);
  v8_kernel<<<dim3(S_ / 8, B_ * NKV), 128, 0, stream>>>(qkvb, V2b);

  attn32_kernel<<<dim3(256), 512, 0, stream>>>(Qb, K2b, V2b, attnb);

  // out-proj: 256x128 tiles, grid 16*16 = 256 (%8==0), 100% CU fill
  gemm8pn_kernel<<<dim3(256), 512, 0, stream>>>(attnb, wob, out, B_ * S_, D_, D_, D_ / 128);
}

// Round 18
// 191.514 us; speedup vs baseline: 1.2494x; 1.2494x over previous
//
#include <hip/hip_runtime.h>
#include <hip/hip_bf16.h>
#include <cstdint>
#include <cstddef>

typedef float f32x4 __attribute__((ext_vector_type(4)));
typedef float f32x16 __attribute__((ext_vector_type(16)));
typedef __bf16 bf16x8 __attribute__((ext_vector_type(8)));
typedef unsigned short us8v __attribute__((ext_vector_type(8)));
typedef unsigned short us4v __attribute__((ext_vector_type(4)));

constexpr int B_ = 2, S_ = 2048, D_ = 2048, NH = 16, NKV = 4, HD = 128;
constexpr int QKV_O = (NH + 2 * NKV) * HD;  // 3072

__device__ __forceinline__ unsigned short f2b(float f) {
  union { float f; uint32_t u; } v{f};
  uint32_t r = v.u + 0x7fffu + ((v.u >> 16) & 1u);  // RNE
  return (unsigned short)(r >> 16);
}

__device__ __forceinline__ float b2f(unsigned short u) {
  union { uint32_t u; float f; } v;
  v.u = ((uint32_t)u) << 16;
  return v.f;
}

__device__ __forceinline__ uint32_t pk2(float a, float b) {
  union { __bf16 h[2]; uint32_t u; } v;
  v.h[0] = (__bf16)a; v.h[1] = (__bf16)b;
  return v.u;
}

__device__ __forceinline__ bf16x8 as_bf(us8v x) {
  union { us8v u; bf16x8 b; } v; v.u = x; return v.b;
}

__device__ __forceinline__ f32x4 mfma16(bf16x8 a, bf16x8 b, f32x4 c) {
  return __builtin_amdgcn_mfma_f32_16x16x32_bf16(a, b, c, 0, 0, 0);
}
__device__ __forceinline__ f32x16 mfma32(bf16x8 a, bf16x8 b, f32x16 c) {
  return __builtin_amdgcn_mfma_f32_32x32x16_bf16(a, b, c, 0, 0, 0);
}

// async global->LDS, 16B per lane; LDS dest = wave-uniform base + lane*16
__device__ __forceinline__ void gload_lds16(const unsigned short* g, unsigned short* l) {
  __builtin_amdgcn_global_load_lds(
      (const __attribute__((address_space(1))) unsigned int*)(uintptr_t)g,
      (__attribute__((address_space(3))) unsigned int*)(uintptr_t)l, 16, 0, 0);
}

// ---------------- fused f32 -> bf16 conversion for x, w_qkv, w_o ----------------
// Segment boundaries in float4 units: x: [0, 2097152), w_qkv: [.., +1572864), w_o: [.., +1048576)
__global__ void f2b_all_kernel(const float* __restrict__ x, const float* __restrict__ wq,
                               const float* __restrict__ wo, unsigned short* __restrict__ xb,
                               unsigned short* __restrict__ wqb, unsigned short* __restrict__ wob) {
  int i = blockIdx.x * blockDim.x + threadIdx.x;
  const int n0 = 2097152, n1 = n0 + 1572864, n2 = n1 + 1048576;
  const float* src;
  unsigned short* dst;
  int j;
  if (i < n0) { src = x; dst = xb; j = i; }
  else if (i < n1) { src = wq; dst = wqb; j = i - n0; }
  else if (i < n2) { src = wo; dst = wob; j = i - n1; }
  else return;
  float4 v = reinterpret_cast<const float4*>(src)[j];
  us4v o;
  o[0] = f2b(v.x); o[1] = f2b(v.y); o[2] = f2b(v.z); o[3] = f2b(v.w);
  reinterpret_cast<us4v*>(dst)[j] = o;
}

// ---------------- RoPE cos/sin table: [S][64] ----------------
__global__ void rope_table_kernel(float* __restrict__ cs, float* __restrict__ sn) {
  int idx = blockIdx.x * blockDim.x + threadIdx.x;
  if (idx >= S_ * 64) return;
  int t = idx >> 6, i = idx & 63;
  float inv = __expf(-((float)(2 * i) / 128.0f) * 9.210340371976184f);
  float fr = (float)t * inv;
  cs[idx] = cosf(fr);
  sn[idx] = sinf(fr);
}

// ---------------- RoPE apply (bf16 qkv in); Q pre-scaled by scale*log2e; K -> K2 ----------------
__global__ void rope_qk_kernel(const unsigned short* __restrict__ qkv, const float* __restrict__ cs,
                               const float* __restrict__ sn, unsigned short* __restrict__ Q,
                               unsigned short* __restrict__ K2) {
  int idx = blockIdx.x * blockDim.x + threadIdx.x;
  if (idx >= B_ * S_ * 20 * 64) return;
  int pr = idx & 63;
  int tmp = idx >> 6;
  int hh = tmp % 20; tmp /= 20;
  int s = tmp % S_;
  int b = tmp / S_;
  int off = (hh < 16) ? hh * HD : NH * HD + (hh - 16) * HD;
  unsigned pv = *reinterpret_cast<const unsigned*>(qkv + (size_t)(b * S_ + s) * QKV_O + off + 2 * pr);
  float vx = b2f((unsigned short)(pv & 0xffff));
  float vy = b2f((unsigned short)(pv >> 16));
  float c0 = cs[s * 64 + pr], s0 = sn[s * 64 + pr];
  // fold attn scale AND log2(e) into Q: softmax runs in exp2 domain
  float mult = (hh < 16) ? 0.12751744f : 1.0f;
  float o0 = (vx * c0 - vy * s0) * mult;
  float o1 = (vx * s0 + vy * c0) * mult;
  unsigned int packed = (unsigned)f2b(o0) | ((unsigned)f2b(o1) << 16);
  if (hh < 16) {
    *reinterpret_cast<unsigned*>(Q + (((size_t)(b * NH + hh) * S_ + s) * HD + 2 * pr)) = packed;
  } else {
    int bk = b * NKV + (hh - 16);
    size_t a = (((size_t)bk * 16 + (pr >> 2)) * S_ + s) * 8 + (pr & 3) * 2;
    *reinterpret_cast<unsigned*>(K2 + a) = packed;
  }
}

// ---------------- V pack: qkv bf16 -> V2 bf16 [bk][s/8][d=128][8] (pure relayout) ----------------
__global__ __launch_bounds__(128) void v8_kernel(const unsigned short* __restrict__ qkv,
                                                 unsigned short* __restrict__ V2) {
  int d = threadIdx.x;          // 0..127
  int g = blockIdx.x;           // s-group 0..255
  int bk = blockIdx.y;          // b*4+kvh
  const unsigned short* src = qkv + (size_t)((bk >> 2) * S_ + g * 8) * QKV_O + (NH + NKV) * HD +
                              (bk & 3) * HD + d;
  us8v o;
#pragma unroll
  for (int j = 0; j < 8; j++) o[j] = src[(size_t)j * QKV_O];
  *reinterpret_cast<us8v*>(V2 + (((size_t)bk * 256 + g) * 128 + d) * 8) = o;
}

// ---------------- bf16 GEMM (256x192 8-phase): C(bf16) = A * B^T, 256 blocks = 1/CU ----------------
__global__ __launch_bounds__(512, 2) void gemm8p192_kernel(const unsigned short* __restrict__ A,
                                                           const unsigned short* __restrict__ Bm,
                                                           unsigned short* __restrict__ C, int M,
                                                           int N, int K, int nbx) {
  __shared__ unsigned short LDS[57344];  // A: 2x16384 elems; B at 32768 + 2x12288 elems
  const int t = threadIdx.x;
  const int lane = t & 63, wid = t >> 6;
  const int wm = wid >> 2, wn = wid & 3;
  const int c = lane & 15, g4 = lane >> 4;
  const int cpx = gridDim.x >> 3;
  const int nid = (blockIdx.x & 7) * cpx + (blockIdx.x >> 3);
  const int m0 = (nid / nbx) * 256, n0 = (nid % nbx) * 192;

  const int sr = t >> 3, ss = t & 7;
  const int sg = ss ^ (sr & 7);
  const unsigned short* pa = A + (size_t)(m0 + sr) * K + sg * 8;
  const unsigned short* pb = Bm + (size_t)(n0 + sr) * K + sg * 8;
  unsigned short* ldw = (unsigned short*)&LDS[wid << 9];

  f32x4 acc[8][3] = {};
  bf16x8 bf[3][2];

#define STAGE_A(buf, j, kk0) \
  gload_lds16(pa + (size_t)(64 * (j)) * K + (kk0), ldw + (buf)*16384 + (j)*4096)
#define STAGE_B(buf, j, kk0) \
  gload_lds16(pb + (size_t)(64 * (j)) * K + (kk0), ldw + 32768 + (buf)*12288 + (j)*4096)

#define LDA(buf, m, kk) \
  as_bf(*reinterpret_cast<const us8v*>( \
      &LDS[(buf)*16384 + (wm * 128 + (m)*16 + c) * 64 + ((((kk) << 2) | g4) ^ (c & 7)) * 8]))
#define LDB(buf, n, kk) \
  as_bf(*reinterpret_cast<const us8v*>( \
      &LDS[32768 + (buf)*12288 + (wn * 48 + (n)*16 + c) * 64 + ((((kk) << 2) | g4) ^ (c & 7)) * 8]))

#pragma unroll
  for (int j = 0; j < 3; j++) STAGE_B(0, j, 0);
#pragma unroll
  for (int j = 0; j < 4; j++) STAGE_A(0, j, 0);
  asm volatile("s_waitcnt vmcnt(0)" ::: "memory");
  __builtin_amdgcn_s_barrier();

  const int NT = K >> 6;
  for (int tt = 0; tt < NT; ++tt) {
    const int cur = tt & 1, nxt = cur ^ 1;
    const int kn = (tt + 1) << 6;
    const bool st = (tt + 1) < NT;
    bf16x8 a00, a01, a10, a11;

#define MFMA_PAIR(mlo)                                    \
  __builtin_amdgcn_s_setprio(1);                          \
  _Pragma("unroll") for (int n = 0; n < 3; n++) {         \
    acc[(mlo)][n] = mfma16(a00, bf[n][0], acc[(mlo)][n]); \
    acc[(mlo) + 1][n] = mfma16(a10, bf[n][0], acc[(mlo) + 1][n]); \
    acc[(mlo)][n] = mfma16(a01, bf[n][1], acc[(mlo)][n]); \
    acc[(mlo) + 1][n] = mfma16(a11, bf[n][1], acc[(mlo) + 1][n]); \
  }                                                       \
  __builtin_amdgcn_s_setprio(0);

    // ---- P0 ----
#pragma unroll
    for (int n = 0; n < 3; n++) { bf[n][0] = LDB(cur, n, 0); bf[n][1] = LDB(cur, n, 1); }
    a00 = LDA(cur, 0, 0); a01 = LDA(cur, 0, 1); a10 = LDA(cur, 1, 0); a11 = LDA(cur, 1, 1);
    if (st) { STAGE_B(nxt, 0, kn); STAGE_B(nxt, 1, kn); }
    __builtin_amdgcn_s_barrier();
    MFMA_PAIR(0)
    __builtin_amdgcn_s_barrier();
    // ---- P1 ----
    a00 = LDA(cur, 2, 0); a01 = LDA(cur, 2, 1); a10 = LDA(cur, 3, 0); a11 = LDA(cur, 3, 1);
    if (st) STAGE_B(nxt, 2, kn);
    asm volatile("s_waitcnt vmcnt(3)" ::: "memory");
    __builtin_amdgcn_s_barrier();
    MFMA_PAIR(2)
    __builtin_amdgcn_s_barrier();
    // ---- P2 ----
    a00 = LDA(cur, 4, 0); a01 = LDA(cur, 4, 1); a10 = LDA(cur, 5, 0); a11 = LDA(cur, 5, 1);
    if (st) { STAGE_A(nxt, 0, kn); STAGE_A(nxt, 2, kn); }
    __builtin_amdgcn_s_barrier();
    MFMA_PAIR(4)
    __builtin_amdgcn_s_barrier();
    // ---- P3 ----
    a00 = LDA(cur, 6, 0); a01 = LDA(cur, 6, 1); a10 = LDA(cur, 7, 0); a11 = LDA(cur, 7, 1);
    if (st) { STAGE_A(nxt, 1, kn); STAGE_A(nxt, 3, kn); }
    asm volatile("s_waitcnt vmcnt(2)" ::: "memory");
    __builtin_amdgcn_s_barrier();
    MFMA_PAIR(6)
    __builtin_amdgcn_s_barrier();
#undef MFMA_PAIR
  }

#pragma unroll
  for (int m = 0; m < 8; m++)
#pragma unroll
    for (int n = 0; n < 3; n++)
#pragma unroll
      for (int r = 0; r < 4; r++)
        C[(size_t)(m0 + wm * 128 + m * 16 + g4 * 4 + r) * N + n0 + wn * 48 + n * 16 + c] =
            f2b(acc[m][n][r]);
#undef STAGE_A
#undef STAGE_B
#undef LDA
#undef LDB
}

// ---------------- bf16 GEMM (256x128 8-phase, f32 C): out-proj, 100% CU fill ----------------
__global__ __launch_bounds__(512, 2) void gemm8pn_kernel(const unsigned short* __restrict__ A,
                                                         const unsigned short* __restrict__ Bm,
                                                         float* __restrict__ C, int M, int N,
                                                         int K, int nbx) {
  __shared__ unsigned short LDS[49152];  // A: [2][16384]; B at 32768 + [2][8192]
  const int t = threadIdx.x;
  const int lane = t & 63, wid = t >> 6;
  const int wm = wid >> 2, wn = wid & 3;
  const int c = lane & 15, g4 = lane >> 4;
  const int cpx = gridDim.x >> 3;
  const int nid = (blockIdx.x & 7) * cpx + (blockIdx.x >> 3);
  const int m0 = (nid / nbx) * 256, n0 = (nid % nbx) * 128;

  const int sr = t >> 3, ss = t & 7;
  const int sg = ss ^ (sr & 7);
  const unsigned short* pa = A + (size_t)(m0 + sr) * K + sg * 8;
  const unsigned short* pb = Bm + (size_t)(n0 + sr) * K + sg * 8;
  unsigned short* ldw = (unsigned short*)&LDS[wid << 9];

  f32x4 acc[8][2] = {};
  bf16x8 bf[2][2];

#define STAGE_A(buf, j, kk0) \
  gload_lds16(pa + (size_t)(64 * (j)) * K + (kk0), ldw + (buf)*16384 + (j)*4096)
#define STAGE_B(buf, j, kk0) \
  gload_lds16(pb + (size_t)(64 * (j)) * K + (kk0), ldw + 32768 + (buf)*8192 + (j)*4096)

#define LDA(buf, m, kk) \
  as_bf(*reinterpret_cast<const us8v*>( \
      &LDS[(buf)*16384 + (wm * 128 + (m)*16 + c) * 64 + ((((kk) << 2) | g4) ^ (c & 7)) * 8]))
#define LDB(buf, n, kk) \
  as_bf(*reinterpret_cast<const us8v*>( \
      &LDS[32768 + (buf)*8192 + (wn * 32 + (n)*16 + c) * 64 + ((((kk) << 2) | g4) ^ (c & 7)) * 8]))

  STAGE_B(0, 0, 0); STAGE_B(0, 1, 0);
#pragma unroll
  for (int j = 0; j < 4; j++) STAGE_A(0, j, 0);
  asm volatile("s_waitcnt vmcnt(0)" ::: "memory");
  __builtin_amdgcn_s_barrier();

  const int NT = K >> 6;
  for (int tt = 0; tt < NT; ++tt) {
    const int cur = tt & 1, nxt = cur ^ 1;
    const int kn = (tt + 1) << 6;
    const bool st = (tt + 1) < NT;
    bf16x8 a00, a01, a10, a11;

#define MFMA_PAIR(mlo)                                    \
  __builtin_amdgcn_s_setprio(1);                          \
  _Pragma("unroll") for (int n = 0; n < 2; n++) {         \
    acc[(mlo)][n] = mfma16(a00, bf[n][0], acc[(mlo)][n]); \
    acc[(mlo) + 1][n] = mfma16(a10, bf[n][0], acc[(mlo) + 1][n]); \
    acc[(mlo)][n] = mfma16(a01, bf[n][1], acc[(mlo)][n]); \
    acc[(mlo) + 1][n] = mfma16(a11, bf[n][1], acc[(mlo) + 1][n]); \
  }                                                       \
  __builtin_amdgcn_s_setprio(0);

    // ---- P0 ----
#pragma unroll
    for (int n = 0; n < 2; n++) { bf[n][0] = LDB(cur, n, 0); bf[n][1] = LDB(cur, n, 1); }
    a00 = LDA(cur, 0, 0); a01 = LDA(cur, 0, 1); a10 = LDA(cur, 1, 0); a11 = LDA(cur, 1, 1);
    if (st) STAGE_B(nxt, 0, kn);
    __builtin_amdgcn_s_barrier();
    MFMA_PAIR(0)
    __builtin_amdgcn_s_barrier();
    // ---- P1 ----
    a00 = LDA(cur, 2, 0); a01 = LDA(cur, 2, 1); a10 = LDA(cur, 3, 0); a11 = LDA(cur, 3, 1);
    if (st) STAGE_B(nxt, 1, kn);
    asm volatile("s_waitcnt vmcnt(2)" ::: "memory");
    __builtin_amdgcn_s_barrier();
    MFMA_PAIR(2)
    __builtin_amdgcn_s_barrier();
    // ---- P2 ----
    a00 = LDA(cur, 4, 0); a01 = LDA(cur, 4, 1); a10 = LDA(cur, 5, 0); a11 = LDA(cur, 5, 1);
    if (st) { STAGE_A(nxt, 0, kn); STAGE_A(nxt, 2, kn); }
    __builtin_amdgcn_s_barrier();
    MFMA_PAIR(4)
    __builtin_amdgcn_s_barrier();
    // ---- P3 ----
    a00 = LDA(cur, 6, 0); a01 = LDA(cur, 6, 1); a10 = LDA(cur, 7, 0); a11 = LDA(cur, 7, 1);
    if (st) { STAGE_A(nxt, 1, kn); STAGE_A(nxt, 3, kn); }
    asm volatile("s_waitcnt vmcnt(2)" ::: "memory");
    __builtin_amdgcn_s_barrier();
    MFMA_PAIR(6)
    __builtin_amdgcn_s_barrier();
#undef MFMA_PAIR
  }

#pragma unroll
  for (int m = 0; m < 8; m++)
#pragma unroll
    for (int n = 0; n < 2; n++)
#pragma unroll
      for (int r = 0; r < 4; r++)
        C[(size_t)(m0 + wm * 128 + m * 16 + g4 * 4 + r) * N + n0 + wn * 32 + n * 16 + c] =
            acc[m][n][r];
#undef STAGE_A
#undef STAGE_B
#undef LDA
#undef LDB
}

// ---------------- Flash attention: SIMD-balanced pairing + XCD-grouped, exp2 softmax (r16) ----------------
__global__ __launch_bounds__(512, 2) void attn32_kernel(const unsigned short* __restrict__ Q,
                                                        const unsigned short* __restrict__ K2,
                                                        const unsigned short* __restrict__ V2,
                                                        unsigned short* __restrict__ O) {
  int t = threadIdx.x;
  int lane = t & 63, wid = t >> 6;
  int l31 = lane & 31, hi = lane >> 5;

  int id = blockIdx.x;
  int g = id & 7, s5 = id >> 3;          // g = (b,kvh) group -> XCD g; s5 = 0..31
  int b = g >> 2, kvh = g & 3;
  int h = kvh * 4 + (s5 & 3);
  int bk = b * NKV + kvh;
  int a = (s5 >> 2) * 4 + (wid & 3);     // pair index 0..31
  int tw = (wid >> 2) ? (63 - a) : a;    // cheap on SIMD w, heavy on same SIMD (w+4)
  int qw = tw * 32;

  const unsigned short* Qp = Q + ((size_t)(b * NH + h) * S_ + qw) * HD + (size_t)l31 * HD + hi * 8;
  const unsigned short* Kp = K2 + (((size_t)bk * 16 + hi) * S_ + l31) * 8;
  const unsigned short* Vp = V2 + (((size_t)bk * 256 + hi) * 128 + l31) * 8;

  bf16x8 qf[8];
#pragma unroll
  for (int kk = 0; kk < 8; kk++)
    qf[kk] = as_bf(*reinterpret_cast<const us8v*>(Qp + kk * 16));

  f32x16 oacc[4] = {};
  float mrow = -1e30f, lsum = 0.0f;

  bf16x8 kA[8], kB[8];

  auto loadK = [&](bf16x8(&kf)[8], int kv) {
    const unsigned short* kp = Kp + (size_t)kv * 8;
#pragma unroll
    for (int kk = 0; kk < 8; kk++)
      kf[kk] = as_bf(*reinterpret_cast<const us8v*>(kp + (size_t)kk * 2 * S_ * 8));
  };

  auto step = [&](bf16x8(&kf)[8], bf16x8(&kn)[8], int kv0) {
    bf16x8 vf[8];
    const unsigned short* vp = Vp + (size_t)kv0 * 128;
#pragma unroll
    for (int dt = 0; dt < 4; dt++) {
      vf[2 * dt] = as_bf(*reinterpret_cast<const us8v*>(vp + dt * 256));
      vf[2 * dt + 1] = as_bf(*reinterpret_cast<const us8v*>(vp + 2048 + dt * 256));
    }
    if (kv0 + 32 <= qw) loadK(kn, kv0 + 32);

    f32x16 sa = {}, sb = {};
    __builtin_amdgcn_s_setprio(1);
#pragma unroll
    for (int kk = 0; kk < 4; kk++) {
      sa = mfma32(kf[2 * kk], qf[2 * kk], sa);
      sb = mfma32(kf[2 * kk + 1], qf[2 * kk + 1], sb);
    }
    __builtin_amdgcn_s_setprio(0);
    f32x16 s = sa + sb;

    if (kv0 == qw) {  // diagonal tile: causal mask
      int qg = qw + l31;
#pragma unroll
      for (int r = 0; r < 16; r++) {
        int kvg = kv0 + (r & 3) + 8 * (r >> 2) + 4 * hi;
        if (kvg > qg) s[r] = -1e30f;
      }
    }

    float pm = fmaxf(s[0], s[1]);
#pragma unroll
    for (int r = 2; r < 16; r++) pm = fmaxf(pm, s[r]);
    pm = fmaxf(pm, __shfl_xor(pm, 32));

    bool nore = __all(pm <= mrow + 11.54f) != 0;  // defer-max, log2 units
    float mn = nore ? mrow : fmaxf(mrow, pm);
    float part = 0.0f;
    uint32_t w[8];
#pragma unroll
    for (int jj = 0; jj < 8; jj++) {
      float e0 = __builtin_amdgcn_exp2f(s[2 * jj] - mn);
      float e1 = __builtin_amdgcn_exp2f(s[2 * jj + 1] - mn);
      part += e0 + e1;
      w[jj] = pk2(e0, e1);
    }
    part += __shfl_xor(part, 32);
    if (nore) {
      lsum += part;
    } else {
      float alpha = __builtin_amdgcn_exp2f(mrow - mn);  // per q-row l31
      lsum = lsum * alpha + part;
      mrow = mn;
#pragma unroll
      for (int r = 0; r < 16; r++) {
        float af = __shfl(alpha, (r & 3) + 8 * (r >> 2) + 4 * hi);
#pragma unroll
        for (int dt = 0; dt < 4; dt++) oacc[dt][r] *= af;
      }
    }

    // ---- P -> A-fragments via lane^32 exchange ----
    uint32_t sw[8];
#pragma unroll
    for (int jj = 0; jj < 8; jj++) sw[jj] = __shfl_xor(w[jj], 32);
    union { uint32_t u[4]; bf16x8 v; } pa0, pa1;
    if (hi == 0) {
      pa0.u[0] = w[0]; pa0.u[1] = w[1]; pa0.u[2] = sw[0]; pa0.u[3] = sw[1];
      pa1.u[0] = w[4]; pa1.u[1] = w[5]; pa1.u[2] = sw[4]; pa1.u[3] = sw[5];
    } else {
      pa0.u[0] = sw[2]; pa0.u[1] = sw[3]; pa0.u[2] = w[2]; pa0.u[3] = w[3];
      pa1.u[0] = sw[6]; pa1.u[1] = sw[7]; pa1.u[2] = w[6]; pa1.u[3] = w[7];
    }

    __builtin_amdgcn_s_setprio(1);
#pragma unroll
    for (int dt = 0; dt < 4; dt++) {
      oacc[dt] = mfma32(pa0.v, vf[2 * dt], oacc[dt]);
      oacc[dt] = mfma32(pa1.v, vf[2 * dt + 1], oacc[dt]);
    }
    __builtin_amdgcn_s_setprio(0);
  };

  loadK(kA, 0);
  int kv0 = 0;
  while (true) {
    step(kA, kB, kv0);
    kv0 += 32;
    if (kv0 > qw) break;
    step(kB, kA, kv0);
    kv0 += 32;
    if (kv0 > qw) break;
  }

  // ---- epilogue: O[q=crow(r,hi)][d=dt*32+l31] ----
  float il = 1.0f / lsum;
  unsigned short* Op = O + ((size_t)b * S_ + qw) * D_ + h * HD;
#pragma unroll
  for (int r = 0; r < 16; r++) {
    int row = (r & 3) + 8 * (r >> 2) + 4 * hi;
    float sc = __shfl(il, row);
#pragma unroll
    for (int dt = 0; dt < 4; dt++)
      Op[(size_t)row * D_ + dt * 32 + l31] = f2b(oacc[dt][r] * sc);
  }
}

extern "C" void kernel_launch(void* const* d_in, const int* in_sizes, int n_in, void* d_out,
                              int out_size, void* d_ws, size_t ws_size, hipStream_t stream) {
  const float* x = (const float*)d_in[0];
  const float* w_qkv = (const float*)d_in[1];
  const float* w_o = (const float*)d_in[2];
  float* out = (float*)d_out;

  char* ws = (char*)d_ws;
  size_t off = 0;
  auto alloc = [&](size_t bytes) -> void* {
    void* p = ws + off;
    off += (bytes + 255) & ~(size_t)255;
    return p;
  };
  const size_t nx = (size_t)B_ * S_ * D_;
  const size_t nwqkv = (size_t)QKV_O * D_;
  const size_t nwo = (size_t)D_ * D_;
  unsigned short* xb = (unsigned short*)alloc(nx * 2);
  unsigned short* wqkvb = (unsigned short*)alloc(nwqkv * 2);
  unsigned short* wob = (unsigned short*)alloc(nwo * 2);
  unsigned short* qkvb = (unsigned short*)alloc((size_t)B_ * S_ * QKV_O * 2);  // bf16
  unsigned short* Qb = (unsigned short*)alloc((size_t)B_ * NH * S_ * HD * 2);
  unsigned short* K2b = (unsigned short*)alloc((size_t)B_ * NKV * S_ * HD * 2);
  unsigned short* V2b = (unsigned short*)alloc((size_t)B_ * NKV * HD * S_ * 2);
  unsigned short* attnb = (unsigned short*)alloc((size_t)B_ * S_ * D_ * 2);
  float* cs = (float*)alloc((size_t)S_ * 64 * 4);
  float* sn = (float*)alloc((size_t)S_ * 64 * 4);

  // fused f32->bf16 for all three inputs: (nx + nwqkv + nwo)/4 = 4718592 float4s
  f2b_all_kernel<<<dim3((4718592 + 255) / 256), 256, 0, stream>>>(x, w_qkv, w_o, xb, wqkvb, wob);
  rope_table_kernel<<<dim3((S_ * 64 + 255) / 256), 256, 0, stream>>>(cs, sn);

  // qkv: 256x192 tiles, grid 16*16 = 256 = exactly 1 block/CU
  gemm8p192_kernel<<<dim3(256), 512, 0, stream>>>(xb, wqkvb, qkvb, B_ * S_, QKV_O, D_,
                                                  QKV_O / 192);

  rope_qk_kernel<<<dim3((B_ * S_ * 20 * 64 + 255) / 256), 256, 0, stream>>>(qkvb, cs, sn, Qb, K2b);
  v8_kernel<<<dim3(S_ / 8, B_ * NKV), 128, 0, stream>>>(qkvb, V2b);

  attn32_kernel<<<dim3(256), 512, 0, stream>>>(Qb, K2b, V2b, attnb);

  // out-proj: 256x128 tiles, grid 16*16 = 256 (%8==0), 100% CU fill
  gemm8pn_kernel<<<dim3(256), 512, 0, stream>>>(attnb, wob, out, B_ * S_, D_, D_, D_ / 128);
}

// Round 19
// 188.867 us; speedup vs baseline: 1.2669x; 1.0140x over previous
//
#include <hip/hip_runtime.h>
#include <hip/hip_bf16.h>
#include <cstdint>
#include <cstddef>

typedef float f32x4 __attribute__((ext_vector_type(4)));
typedef float f32x16 __attribute__((ext_vector_type(16)));
typedef __bf16 bf16x8 __attribute__((ext_vector_type(8)));
typedef unsigned short us8v __attribute__((ext_vector_type(8)));
typedef unsigned short us4v __attribute__((ext_vector_type(4)));

constexpr int B_ = 2, S_ = 2048, D_ = 2048, NH = 16, NKV = 4, HD = 128;
constexpr int QKV_O = (NH + 2 * NKV) * HD;  // 3072

__device__ __forceinline__ unsigned short f2b(float f) {
  union { float f; uint32_t u; } v{f};
  uint32_t r = v.u + 0x7fffu + ((v.u >> 16) & 1u);  // RNE
  return (unsigned short)(r >> 16);
}

__device__ __forceinline__ float b2f(unsigned short u) {
  union { uint32_t u; float f; } v;
  v.u = ((uint32_t)u) << 16;
  return v.f;
}

__device__ __forceinline__ uint32_t pk2(float a, float b) {
  union { __bf16 h[2]; uint32_t u; } v;
  v.h[0] = (__bf16)a; v.h[1] = (__bf16)b;
  return v.u;
}

__device__ __forceinline__ bf16x8 as_bf(us8v x) {
  union { us8v u; bf16x8 b; } v; v.u = x; return v.b;
}

__device__ __forceinline__ f32x4 mfma16(bf16x8 a, bf16x8 b, f32x4 c) {
  return __builtin_amdgcn_mfma_f32_16x16x32_bf16(a, b, c, 0, 0, 0);
}
__device__ __forceinline__ f32x16 mfma32(bf16x8 a, bf16x8 b, f32x16 c) {
  return __builtin_amdgcn_mfma_f32_32x32x16_bf16(a, b, c, 0, 0, 0);
}

// async global->LDS, 16B per lane; LDS dest = wave-uniform base + lane*16
__device__ __forceinline__ void gload_lds16(const unsigned short* g, unsigned short* l) {
  __builtin_amdgcn_global_load_lds(
      (const __attribute__((address_space(1))) unsigned int*)(uintptr_t)g,
      (__attribute__((address_space(3))) unsigned int*)(uintptr_t)l, 16, 0, 0);
}

// ---------------- fused prep: f32->bf16 (x, w_qkv, w_o) + RoPE cos/sin table ----------------
// float4 segments: x [0,2097152), w_qkv [..,+1572864), w_o [..,+1048576); then 131072 table elems.
__global__ void prep_kernel(const float* __restrict__ x, const float* __restrict__ wq,
                            const float* __restrict__ wo, unsigned short* __restrict__ xb,
                            unsigned short* __restrict__ wqb, unsigned short* __restrict__ wob,
                            float* __restrict__ cs, float* __restrict__ sn) {
  int i = blockIdx.x * blockDim.x + threadIdx.x;
  const int n0 = 2097152, n1 = n0 + 1572864, n2 = n1 + 1048576, n3 = n2 + S_ * 64;
  if (i < n2) {
    const float* src;
    unsigned short* dst;
    int j;
    if (i < n0) { src = x; dst = xb; j = i; }
    else if (i < n1) { src = wq; dst = wqb; j = i - n0; }
    else { src = wo; dst = wob; j = i - n1; }
    float4 v = reinterpret_cast<const float4*>(src)[j];
    us4v o;
    o[0] = f2b(v.x); o[1] = f2b(v.y); o[2] = f2b(v.z); o[3] = f2b(v.w);
    reinterpret_cast<us4v*>(dst)[j] = o;
  } else if (i < n3) {
    int idx = i - n2;
    int t = idx >> 6, ii = idx & 63;
    float inv = __expf(-((float)(2 * ii) / 128.0f) * 9.210340371976184f);
    float fr = (float)t * inv;
    cs[idx] = cosf(fr);
    sn[idx] = sinf(fr);
  }
}

// ---------------- RoPE apply (bf16 qkv in); Q pre-scaled by scale*log2e; K -> K2 ----------------
__global__ void rope_qk_kernel(const unsigned short* __restrict__ qkv, const float* __restrict__ cs,
                               const float* __restrict__ sn, unsigned short* __restrict__ Q,
                               unsigned short* __restrict__ K2) {
  int idx = blockIdx.x * blockDim.x + threadIdx.x;
  if (idx >= B_ * S_ * 20 * 64) return;
  int pr = idx & 63;
  int tmp = idx >> 6;
  int hh = tmp % 20; tmp /= 20;
  int s = tmp % S_;
  int b = tmp / S_;
  int off = (hh < 16) ? hh * HD : NH * HD + (hh - 16) * HD;
  unsigned pv = *reinterpret_cast<const unsigned*>(qkv + (size_t)(b * S_ + s) * QKV_O + off + 2 * pr);
  float vx = b2f((unsigned short)(pv & 0xffff));
  float vy = b2f((unsigned short)(pv >> 16));
  float c0 = cs[s * 64 + pr], s0 = sn[s * 64 + pr];
  // fold attn scale AND log2(e) into Q: softmax runs in exp2 domain
  float mult = (hh < 16) ? 0.12751744f : 1.0f;
  float o0 = (vx * c0 - vy * s0) * mult;
  float o1 = (vx * s0 + vy * c0) * mult;
  unsigned int packed = (unsigned)f2b(o0) | ((unsigned)f2b(o1) << 16);
  if (hh < 16) {
    *reinterpret_cast<unsigned*>(Q + (((size_t)(b * NH + hh) * S_ + s) * HD + 2 * pr)) = packed;
  } else {
    int bk = b * NKV + (hh - 16);
    size_t a = (((size_t)bk * 16 + (pr >> 2)) * S_ + s) * 8 + (pr & 3) * 2;
    *reinterpret_cast<unsigned*>(K2 + a) = packed;
  }
}

// ---------------- V pack: qkv bf16 -> V2 bf16 [bk][s/8][d=128][8] (pure relayout) ----------------
__global__ __launch_bounds__(128) void v8_kernel(const unsigned short* __restrict__ qkv,
                                                 unsigned short* __restrict__ V2) {
  int d = threadIdx.x;          // 0..127
  int g = blockIdx.x;           // s-group 0..255
  int bk = blockIdx.y;          // b*4+kvh
  const unsigned short* src = qkv + (size_t)((bk >> 2) * S_ + g * 8) * QKV_O + (NH + NKV) * HD +
                              (bk & 3) * HD + d;
  us8v o;
#pragma unroll
  for (int j = 0; j < 8; j++) o[j] = src[(size_t)j * QKV_O];
  *reinterpret_cast<us8v*>(V2 + (((size_t)bk * 256 + g) * 128 + d) * 8) = o;
}

// ---------------- bf16 GEMM (256x192 8-phase): C(bf16) = A * B^T, 256 blocks = 1/CU ----------------
__global__ __launch_bounds__(512, 2) void gemm8p192_kernel(const unsigned short* __restrict__ A,
                                                           const unsigned short* __restrict__ Bm,
                                                           unsigned short* __restrict__ C, int M,
                                                           int N, int K, int nbx) {
  __shared__ unsigned short LDS[57344];  // A: 2x16384 elems; B at 32768 + 2x12288 elems
  const int t = threadIdx.x;
  const int lane = t & 63, wid = t >> 6;
  const int wm = wid >> 2, wn = wid & 3;
  const int c = lane & 15, g4 = lane >> 4;
  const int cpx = gridDim.x >> 3;
  const int nid = (blockIdx.x & 7) * cpx + (blockIdx.x >> 3);
  const int m0 = (nid / nbx) * 256, n0 = (nid % nbx) * 192;

  const int sr = t >> 3, ss = t & 7;
  const int sg = ss ^ (sr & 7);
  const unsigned short* pa = A + (size_t)(m0 + sr) * K + sg * 8;
  const unsigned short* pb = Bm + (size_t)(n0 + sr) * K + sg * 8;
  unsigned short* ldw = (unsigned short*)&LDS[wid << 9];

  f32x4 acc[8][3] = {};
  bf16x8 bf[3][2];

#define STAGE_A(buf, j, kk0) \
  gload_lds16(pa + (size_t)(64 * (j)) * K + (kk0), ldw + (buf)*16384 + (j)*4096)
#define STAGE_B(buf, j, kk0) \
  gload_lds16(pb + (size_t)(64 * (j)) * K + (kk0), ldw + 32768 + (buf)*12288 + (j)*4096)

#define LDA(buf, m, kk) \
  as_bf(*reinterpret_cast<const us8v*>( \
      &LDS[(buf)*16384 + (wm * 128 + (m)*16 + c) * 64 + ((((kk) << 2) | g4) ^ (c & 7)) * 8]))
#define LDB(buf, n, kk) \
  as_bf(*reinterpret_cast<const us8v*>( \
      &LDS[32768 + (buf)*12288 + (wn * 48 + (n)*16 + c) * 64 + ((((kk) << 2) | g4) ^ (c & 7)) * 8]))

#pragma unroll
  for (int j = 0; j < 3; j++) STAGE_B(0, j, 0);
#pragma unroll
  for (int j = 0; j < 4; j++) STAGE_A(0, j, 0);
  asm volatile("s_waitcnt vmcnt(0)" ::: "memory");
  __builtin_amdgcn_s_barrier();

  const int NT = K >> 6;
  for (int tt = 0; tt < NT; ++tt) {
    const int cur = tt & 1, nxt = cur ^ 1;
    const int kn = (tt + 1) << 6;
    const bool st = (tt + 1) < NT;
    bf16x8 a00, a01, a10, a11;

#define MFMA_PAIR(mlo)                                    \
  __builtin_amdgcn_s_setprio(1);                          \
  _Pragma("unroll") for (int n = 0; n < 3; n++) {         \
    acc[(mlo)][n] = mfma16(a00, bf[n][0], acc[(mlo)][n]); \
    acc[(mlo) + 1][n] = mfma16(a10, bf[n][0], acc[(mlo) + 1][n]); \
    acc[(mlo)][n] = mfma16(a01, bf[n][1], acc[(mlo)][n]); \
    acc[(mlo) + 1][n] = mfma16(a11, bf[n][1], acc[(mlo) + 1][n]); \
  }                                                       \
  __builtin_amdgcn_s_setprio(0);

    // ---- P0 ----
#pragma unroll
    for (int n = 0; n < 3; n++) { bf[n][0] = LDB(cur, n, 0); bf[n][1] = LDB(cur, n, 1); }
    a00 = LDA(cur, 0, 0); a01 = LDA(cur, 0, 1); a10 = LDA(cur, 1, 0); a11 = LDA(cur, 1, 1);
    if (st) { STAGE_B(nxt, 0, kn); STAGE_B(nxt, 1, kn); }
    __builtin_amdgcn_s_barrier();
    MFMA_PAIR(0)
    __builtin_amdgcn_s_barrier();
    // ---- P1 ----
    a00 = LDA(cur, 2, 0); a01 = LDA(cur, 2, 1); a10 = LDA(cur, 3, 0); a11 = LDA(cur, 3, 1);
    if (st) STAGE_B(nxt, 2, kn);
    asm volatile("s_waitcnt vmcnt(3)" ::: "memory");
    __builtin_amdgcn_s_barrier();
    MFMA_PAIR(2)
    __builtin_amdgcn_s_barrier();
    // ---- P2 ----
    a00 = LDA(cur, 4, 0); a01 = LDA(cur, 4, 1); a10 = LDA(cur, 5, 0); a11 = LDA(cur, 5, 1);
    if (st) { STAGE_A(nxt, 0, kn); STAGE_A(nxt, 2, kn); }
    __builtin_amdgcn_s_barrier();
    MFMA_PAIR(4)
    __builtin_amdgcn_s_barrier();
    // ---- P3 ----
    a00 = LDA(cur, 6, 0); a01 = LDA(cur, 6, 1); a10 = LDA(cur, 7, 0); a11 = LDA(cur, 7, 1);
    if (st) { STAGE_A(nxt, 1, kn); STAGE_A(nxt, 3, kn); }
    asm volatile("s_waitcnt vmcnt(2)" ::: "memory");
    __builtin_amdgcn_s_barrier();
    MFMA_PAIR(6)
    __builtin_amdgcn_s_barrier();
#undef MFMA_PAIR
  }

#pragma unroll
  for (int m = 0; m < 8; m++)
#pragma unroll
    for (int n = 0; n < 3; n++)
#pragma unroll
      for (int r = 0; r < 4; r++)
        C[(size_t)(m0 + wm * 128 + m * 16 + g4 * 4 + r) * N + n0 + wn * 48 + n * 16 + c] =
            f2b(acc[m][n][r]);
#undef STAGE_A
#undef STAGE_B
#undef LDA
#undef LDB
}

// ---------------- bf16 GEMM (256x128 8-phase, f32 C): out-proj, 100% CU fill ----------------
__global__ __launch_bounds__(512, 2) void gemm8pn_kernel(const unsigned short* __restrict__ A,
                                                         const unsigned short* __restrict__ Bm,
                                                         float* __restrict__ C, int M, int N,
                                                         int K, int nbx) {
  __shared__ unsigned short LDS[49152];  // A: [2][16384]; B at 32768 + [2][8192]
  const int t = threadIdx.x;
  const int lane = t & 63, wid = t >> 6;
  const int wm = wid >> 2, wn = wid & 3;
  const int c = lane & 15, g4 = lane >> 4;
  const int cpx = gridDim.x >> 3;
  const int nid = (blockIdx.x & 7) * cpx + (blockIdx.x >> 3);
  const int m0 = (nid / nbx) * 256, n0 = (nid % nbx) * 128;

  const int sr = t >> 3, ss = t & 7;
  const int sg = ss ^ (sr & 7);
  const unsigned short* pa = A + (size_t)(m0 + sr) * K + sg * 8;
  const unsigned short* pb = Bm + (size_t)(n0 + sr) * K + sg * 8;
  unsigned short* ldw = (unsigned short*)&LDS[wid << 9];

  f32x4 acc[8][2] = {};
  bf16x8 bf[2][2];

#define STAGE_A(buf, j, kk0) \
  gload_lds16(pa + (size_t)(64 * (j)) * K + (kk0), ldw + (buf)*16384 + (j)*4096)
#define STAGE_B(buf, j, kk0) \
  gload_lds16(pb + (size_t)(64 * (j)) * K + (kk0), ldw + 32768 + (buf)*8192 + (j)*4096)

#define LDA(buf, m, kk) \
  as_bf(*reinterpret_cast<const us8v*>( \
      &LDS[(buf)*16384 + (wm * 128 + (m)*16 + c) * 64 + ((((kk) << 2) | g4) ^ (c & 7)) * 8]))
#define LDB(buf, n, kk) \
  as_bf(*reinterpret_cast<const us8v*>( \
      &LDS[32768 + (buf)*8192 + (wn * 32 + (n)*16 + c) * 64 + ((((kk) << 2) | g4) ^ (c & 7)) * 8]))

  STAGE_B(0, 0, 0); STAGE_B(0, 1, 0);
#pragma unroll
  for (int j = 0; j < 4; j++) STAGE_A(0, j, 0);
  asm volatile("s_waitcnt vmcnt(0)" ::: "memory");
  __builtin_amdgcn_s_barrier();

  const int NT = K >> 6;
  for (int tt = 0; tt < NT; ++tt) {
    const int cur = tt & 1, nxt = cur ^ 1;
    const int kn = (tt + 1) << 6;
    const bool st = (tt + 1) < NT;
    bf16x8 a00, a01, a10, a11;

#define MFMA_PAIR(mlo)                                    \
  __builtin_amdgcn_s_setprio(1);                          \
  _Pragma("unroll") for (int n = 0; n < 2; n++) {         \
    acc[(mlo)][n] = mfma16(a00, bf[n][0], acc[(mlo)][n]); \
    acc[(mlo) + 1][n] = mfma16(a10, bf[n][0], acc[(mlo) + 1][n]); \
    acc[(mlo)][n] = mfma16(a01, bf[n][1], acc[(mlo)][n]); \
    acc[(mlo) + 1][n] = mfma16(a11, bf[n][1], acc[(mlo) + 1][n]); \
  }                                                       \
  __builtin_amdgcn_s_setprio(0);

    // ---- P0 ----
#pragma unroll
    for (int n = 0; n < 2; n++) { bf[n][0] = LDB(cur, n, 0); bf[n][1] = LDB(cur, n, 1); }
    a00 = LDA(cur, 0, 0); a01 = LDA(cur, 0, 1); a10 = LDA(cur, 1, 0); a11 = LDA(cur, 1, 1);
    if (st) STAGE_B(nxt, 0, kn);
    __builtin_amdgcn_s_barrier();
    MFMA_PAIR(0)
    __builtin_amdgcn_s_barrier();
    // ---- P1 ----
    a00 = LDA(cur, 2, 0); a01 = LDA(cur, 2, 1); a10 = LDA(cur, 3, 0); a11 = LDA(cur, 3, 1);
    if (st) STAGE_B(nxt, 1, kn);
    asm volatile("s_waitcnt vmcnt(2)" ::: "memory");
    __builtin_amdgcn_s_barrier();
    MFMA_PAIR(2)
    __builtin_amdgcn_s_barrier();
    // ---- P2 ----
    a00 = LDA(cur, 4, 0); a01 = LDA(cur, 4, 1); a10 = LDA(cur, 5, 0); a11 = LDA(cur, 5, 1);
    if (st) { STAGE_A(nxt, 0, kn); STAGE_A(nxt, 2, kn); }
    __builtin_amdgcn_s_barrier();
    MFMA_PAIR(4)
    __builtin_amdgcn_s_barrier();
    // ---- P3 ----
    a00 = LDA(cur, 6, 0); a01 = LDA(cur, 6, 1); a10 = LDA(cur, 7, 0); a11 = LDA(cur, 7, 1);
    if (st) { STAGE_A(nxt, 1, kn); STAGE_A(nxt, 3, kn); }
    asm volatile("s_waitcnt vmcnt(2)" ::: "memory");
    __builtin_amdgcn_s_barrier();
    MFMA_PAIR(6)
    __builtin_amdgcn_s_barrier();
#undef MFMA_PAIR
  }

#pragma unroll
  for (int m = 0; m < 8; m++)
#pragma unroll
    for (int n = 0; n < 2; n++)
#pragma unroll
      for (int r = 0; r < 4; r++)
        C[(size_t)(m0 + wm * 128 + m * 16 + g4 * 4 + r) * N + n0 + wn * 32 + n * 16 + c] =
            acc[m][n][r];
#undef STAGE_A
#undef STAGE_B
#undef LDA
#undef LDB
}

// ---------------- Flash attention: SIMD-balanced pairing + XCD-grouped, exp2 softmax (r16) ----------------
__global__ __launch_bounds__(512, 2) void attn32_kernel(const unsigned short* __restrict__ Q,
                                                        const unsigned short* __restrict__ K2,
                                                        const unsigned short* __restrict__ V2,
                                                        unsigned short* __restrict__ O) {
  int t = threadIdx.x;
  int lane = t & 63, wid = t >> 6;
  int l31 = lane & 31, hi = lane >> 5;

  int id = blockIdx.x;
  int g = id & 7, s5 = id >> 3;          // g = (b,kvh) group -> XCD g; s5 = 0..31
  int b = g >> 2, kvh = g & 3;
  int h = kvh * 4 + (s5 & 3);
  int bk = b * NKV + kvh;
  int a = (s5 >> 2) * 4 + (wid & 3);     // pair index 0..31
  int tw = (wid >> 2) ? (63 - a) : a;    // cheap on SIMD w, heavy on same SIMD (w+4)
  int qw = tw * 32;

  const unsigned short* Qp = Q + ((size_t)(b * NH + h) * S_ + qw) * HD + (size_t)l31 * HD + hi * 8;
  const unsigned short* Kp = K2 + (((size_t)bk * 16 + hi) * S_ + l31) * 8;
  const unsigned short* Vp = V2 + (((size_t)bk * 256 + hi) * 128 + l31) * 8;

  bf16x8 qf[8];
#pragma unroll
  for (int kk = 0; kk < 8; kk++)
    qf[kk] = as_bf(*reinterpret_cast<const us8v*>(Qp + kk * 16));

  f32x16 oacc[4] = {};
  float mrow = -1e30f, lsum = 0.0f;

  bf16x8 kA[8], kB[8];

  auto loadK = [&](bf16x8(&kf)[8], int kv) {
    const unsigned short* kp = Kp + (size_t)kv * 8;
#pragma unroll
    for (int kk = 0; kk < 8; kk++)
      kf[kk] = as_bf(*reinterpret_cast<const us8v*>(kp + (size_t)kk * 2 * S_ * 8));
  };

  auto step = [&](bf16x8(&kf)[8], bf16x8(&kn)[8], int kv0) {
    bf16x8 vf[8];
    const unsigned short* vp = Vp + (size_t)kv0 * 128;
#pragma unroll
    for (int dt = 0; dt < 4; dt++) {
      vf[2 * dt] = as_bf(*reinterpret_cast<const us8v*>(vp + dt * 256));
      vf[2 * dt + 1] = as_bf(*reinterpret_cast<const us8v*>(vp + 2048 + dt * 256));
    }
    if (kv0 + 32 <= qw) loadK(kn, kv0 + 32);

    f32x16 sa = {}, sb = {};
    __builtin_amdgcn_s_setprio(1);
#pragma unroll
    for (int kk = 0; kk < 4; kk++) {
      sa = mfma32(kf[2 * kk], qf[2 * kk], sa);
      sb = mfma32(kf[2 * kk + 1], qf[2 * kk + 1], sb);
    }
    __builtin_amdgcn_s_setprio(0);
    f32x16 s = sa + sb;

    if (kv0 == qw) {  // diagonal tile: causal mask
      int qg = qw + l31;
#pragma unroll
      for (int r = 0; r < 16; r++) {
        int kvg = kv0 + (r & 3) + 8 * (r >> 2) + 4 * hi;
        if (kvg > qg) s[r] = -1e30f;
      }
    }

    float pm = fmaxf(s[0], s[1]);
#pragma unroll
    for (int r = 2; r < 16; r++) pm = fmaxf(pm, s[r]);
    pm = fmaxf(pm, __shfl_xor(pm, 32));

    bool nore = __all(pm <= mrow + 11.54f) != 0;  // defer-max, log2 units
    float mn = nore ? mrow : fmaxf(mrow, pm);
    float part = 0.0f;
    uint32_t w[8];
#pragma unroll
    for (int jj = 0; jj < 8; jj++) {
      float e0 = __builtin_amdgcn_exp2f(s[2 * jj] - mn);
      float e1 = __builtin_amdgcn_exp2f(s[2 * jj + 1] - mn);
      part += e0 + e1;
      w[jj] = pk2(e0, e1);
    }
    part += __shfl_xor(part, 32);
    if (nore) {
      lsum += part;
    } else {
      float alpha = __builtin_amdgcn_exp2f(mrow - mn);  // per q-row l31
      lsum = lsum * alpha + part;
      mrow = mn;
#pragma unroll
      for (int r = 0; r < 16; r++) {
        float af = __shfl(alpha, (r & 3) + 8 * (r >> 2) + 4 * hi);
#pragma unroll
        for (int dt = 0; dt < 4; dt++) oacc[dt][r] *= af;
      }
    }

    // ---- P -> A-fragments via lane^32 exchange ----
    uint32_t sw[8];
#pragma unroll
    for (int jj = 0; jj < 8; jj++) sw[jj] = __shfl_xor(w[jj], 32);
    union { uint32_t u[4]; bf16x8 v; } pa0, pa1;
    if (hi == 0) {
      pa0.u[0] = w[0]; pa0.u[1] = w[1]; pa0.u[2] = sw[0]; pa0.u[3] = sw[1];
      pa1.u[0] = w[4]; pa1.u[1] = w[5]; pa1.u[2] = sw[4]; pa1.u[3] = sw[5];
    } else {
      pa0.u[0] = sw[2]; pa0.u[1] = sw[3]; pa0.u[2] = w[2]; pa0.u[3] = w[3];
      pa1.u[0] = sw[6]; pa1.u[1] = sw[7]; pa1.u[2] = w[6]; pa1.u[3] = w[7];
    }

    __builtin_amdgcn_s_setprio(1);
#pragma unroll
    for (int dt = 0; dt < 4; dt++) {
      oacc[dt] = mfma32(pa0.v, vf[2 * dt], oacc[dt]);
      oacc[dt] = mfma32(pa1.v, vf[2 * dt + 1], oacc[dt]);
    }
    __builtin_amdgcn_s_setprio(0);
  };

  loadK(kA, 0);
  int kv0 = 0;
  while (true) {
    step(kA, kB, kv0);
    kv0 += 32;
    if (kv0 > qw) break;
    step(kB, kA, kv0);
    kv0 += 32;
    if (kv0 > qw) break;
  }

  // ---- epilogue: O[q=crow(r,hi)][d=dt*32+l31] ----
  float il = 1.0f / lsum;
  unsigned short* Op = O + ((size_t)b * S_ + qw) * D_ + h * HD;
#pragma unroll
  for (int r = 0; r < 16; r++) {
    int row = (r & 3) + 8 * (r >> 2) + 4 * hi;
    float sc = __shfl(il, row);
#pragma unroll
    for (int dt = 0; dt < 4; dt++)
      Op[(size_t)row * D_ + dt * 32 + l31] = f2b(oacc[dt][r] * sc);
  }
}

extern "C" void kernel_launch(void* const* d_in, const int* in_sizes, int n_in, void* d_out,
                              int out_size, void* d_ws, size_t ws_size, hipStream_t stream) {
  const float* x = (const float*)d_in[0];
  const float* w_qkv = (const float*)d_in[1];
  const float* w_o = (const float*)d_in[2];
  float* out = (float*)d_out;

  char* ws = (char*)d_ws;
  size_t off = 0;
  auto alloc = [&](size_t bytes) -> void* {
    void* p = ws + off;
    off += (bytes + 255) & ~(size_t)255;
    return p;
  };
  const size_t nx = (size_t)B_ * S_ * D_;
  const size_t nwqkv = (size_t)QKV_O * D_;
  const size_t nwo = (size_t)D_ * D_;
  unsigned short* xb = (unsigned short*)alloc(nx * 2);
  unsigned short* wqkvb = (unsigned short*)alloc(nwqkv * 2);
  unsigned short* wob = (unsigned short*)alloc(nwo * 2);
  unsigned short* qkvb = (unsigned short*)alloc((size_t)B_ * S_ * QKV_O * 2);  // bf16
  unsigned short* Qb = (unsigned short*)alloc((size_t)B_ * NH * S_ * HD * 2);
  unsigned short* K2b = (unsigned short*)alloc((size_t)B_ * NKV * S_ * HD * 2);
  unsigned short* V2b = (unsigned short*)alloc((size_t)B_ * NKV * HD * S_ * 2);
  unsigned short* attnb = (unsigned short*)alloc((size_t)B_ * S_ * D_ * 2);
  float* cs = (float*)alloc((size_t)S_ * 64 * 4);
  float* sn = (float*)alloc((size_t)S_ * 64 * 4);

  // fused prep: f32->bf16 (4718592 float4s) + cos/sin table (131072 elems)
  prep_kernel<<<dim3((4718592 + 131072 + 255) / 256), 256, 0, stream>>>(x, w_qkv, w_o, xb, wqkvb,
                                                                        wob, cs, sn);

  // qkv: 256x192 tiles, grid 16*16 = 256 = exactly 1 block/CU
  gemm8p192_kernel<<<dim3(256), 512, 0, stream>>>(xb, wqkvb, qkvb, B_ * S_, QKV_O, D_,
                                                  QKV_O / 192);

  rope_qk_kernel<<<dim3((B_ * S_ * 20 * 64 + 255) / 256), 256, 0, stream>>>(qkvb, cs, sn, Qb, K2b);
  v8_kernel<<<dim3(S_ / 8, B_ * NKV), 128, 0, stream>>>(qkvb, V2b);

  attn32_kernel<<<dim3(256), 512, 0, stream>>>(Qb, K2b, V2b, attnb);

  // out-proj: 256x128 tiles, grid 16*16 = 256 (%8==0), 100% CU fill
  gemm8pn_kernel<<<dim3(256), 512, 0, stream>>>(attnb, wob, out, B_ * S_, D_, D_, D_ / 128);
}